// Round 4
// baseline (209.143 us; speedup 1.0000x reference)
//
#include <hip/hip_runtime.h>
#include <stdint.h>

#define S 64
#define NSQ 32
#define Lc 2048
#define Cc 512
#define Ec 128
#define OUT_H (S*NSQ*Lc)   /* 4194304 */

#define TLL 128            /* l-tile cols incl 2-halo */
#define ULL 126            /* useful cols per tile */
#define NT 17              /* ceil(2048/126) */

typedef __bf16 bf16x8 __attribute__((ext_vector_type(8)));
typedef float floatx4 __attribute__((ext_vector_type(4)));

__device__ __forceinline__ unsigned short f2bf(float f){
  union { float f; uint32_t u; } v; v.f = f;
  uint32_t r = v.u + 0x7fffu + ((v.u >> 16) & 1u);
  return (unsigned short)(r >> 16);
}

// packed f32x2 -> bf16x2 (RNE), 1 instruction on gfx950
__device__ __forceinline__ uint32_t cvt_pk_bf16(float lo, float hi){
  uint32_t r;
  asm("v_cvt_pk_bf16_f32 %0, %1, %2" : "=v"(r) : "v"(lo), "v"(hi));
  return r;
}

// XOR-swizzled LDS offset (shorts) for the x/x2 tile (row stride 512).
__device__ __forceinline__ int xoff(int row, int cg) {
  return row*512 + (((cg) ^ (row & 7)) << 3);
}

// ---------------------------------------------------------------------------
// k_prep: unchanged from R3 (adapt split 16-way; packs on blocks<512).
// ---------------------------------------------------------------------------
__global__ void k_prep(const float* __restrict__ emb,
                       const float* __restrict__ Wa, const float* __restrict__ ba,
                       const float* __restrict__ Wb, const float* __restrict__ bb,
                       const float* __restrict__ W1, const float* __restrict__ W2,
                       float* __restrict__ dynW, float* __restrict__ dynB,
                       unsigned short* __restrict__ W1p, unsigned short* __restrict__ W2p,
                       float* __restrict__ out)
{
  __shared__ float embl[Ec];
  int tid = threadIdx.x;
  int b = blockIdx.x;          // 1024 blocks, 16 per sample for adapt
  int s = b >> 4, g = b & 15;
  if (tid < Ec) embl[tid] = emb[s*Ec + tid];
  __syncthreads();
  {
    int w = tid >> 6, lane = tid & 63, le = lane & 31, rh = lane >> 5;
    float4 ev = *(const float4*)&embl[le*4];
    int base_o = g*128 + w*32;
    #pragma unroll 4
    for (int p = 0; p < 16; p++) {
      int ro = base_o + p*2 + rh;
      bool isA = ro < 1536;
      const float* rp = isA ? (Wa + ro*Ec) : (Wb + (ro - 1536)*Ec);
      float4 wv = *(const float4*)&rp[le*4];
      float part = wv.x*ev.x + wv.y*ev.y + wv.z*ev.z + wv.w*ev.w;
      part += __shfl_xor(part, 1, 32);
      part += __shfl_xor(part, 2, 32);
      part += __shfl_xor(part, 4, 32);
      part += __shfl_xor(part, 8, 32);
      part += __shfl_xor(part, 16, 32);
      if (le == 0) {
        if (isA) {
          int ch = ro / 3, k = ro - ch*3;
          int cgc = ch >> 3, j = (ch & 7)*3 + k;
          dynW[s*1536 + (j >> 2)*256 + cgc*4 + (j & 3)] = part + ba[ro];
        } else {
          dynB[s*Cc + (ro - 1536)] = part + bb[ro - 1536];
        }
      }
    }
  }

  if (b < 512) {
    int gtid = b*256 + tid;      // 0..131071
    {
      int d0 = gtid*2;
      int j0 = d0 & 7;
      int lane = (d0 >> 3) & 63;
      int frag = d0 >> 9;
      int o16 = frag & 31, ch = frag >> 5;
      int oo = o16*16 + (lane & 15);
      int cc = ch*32 + (lane >> 4)*8 + j0;
      float2 wv = *(const float2*)&W1[oo*512 + cc];
      ((uint32_t*)W1p)[gtid] = cvt_pk_bf16(wv.x, wv.y);
    }
    if (gtid < 49152) {
      int e = gtid;
      int jj = e / 1536;
      int r = e - jj*1536;
      int c = r / 3, k = r - c*3;
      int cc = c >> 5, hi = (c >> 3) & 3, j = c & 7;
      int jh = jj >> 4, lo = jj & 15;
      int lane = hi*16 + lo;
      int frag = (k*2 + jh)*16 + cc;
      W2p[(frag << 9) + lane*8 + j] = f2bf(W2[e]);
    }
    if (gtid < S) out[OUT_H + gtid] = 0.f;   // logdet accumulators
  }
}

// ---------------------------------------------------------------------------
// k_fused13: 128-col l-tile (126 useful) — halves the L2 weight re-stream:
//  - blocks 2176 -> 1088: W1p traffic per lpos halved (phase A now MFMA-bound)
//  - phase B: wave = (lq 0..3 of 32 lpos, jh): W2p per lpos halved too
//  - acc[4][8] (128 AGPR), 1 block/CU (150 KiB LDS), 8 waves/CU
// x2 col ll <-> global l = t*126 - 1 + ll; valid outputs ll in [1,126].
// ---------------------------------------------------------------------------
__global__ void __launch_bounds__(512, 2) k_fused13(
    const float* __restrict__ h,
    const unsigned short* __restrict__ W1p, const float* __restrict__ b1,
    const unsigned short* __restrict__ W2p, const float* __restrict__ b2,
    const float* __restrict__ dynW, const float* __restrict__ dynB,
    float* __restrict__ out)
{
  extern __shared__ char smem[];
  float* hs  = (float*)smem;                              // [16][132] f32 (8448 B)
  float* dws = (float*)(smem + 8448);                     // [6][64] float4 (6144 B)
  float* x3b = (float*)smem;                              // [128][37] f32 (aliases stage)
  unsigned short* xt = (unsigned short*)(smem + 18944);   // [128][512] swizzled (128 KiB)
  float* red = (float*)(smem + 150016);                   // [8]

  int tid = threadIdx.x;
  int t = blockIdx.x, s = blockIdx.y;
  int lb = t*ULL - 1;          // global l of x2 col ll=0
  int w = tid >> 6, ln16 = tid & 15, quad = (tid & 63) >> 4;
  int lane8 = (tid & 63)*8;

  const float* hb = h + s*(NSQ*Lc);

  // -------- stage h window + dyn weights (+ bias from L2, pre-barrier) -----
  for (int i = tid; i < 16*132; i += 512) {
    int r = i / 132, col = i - r*132;
    int gl = t*ULL - 2 + col;                 // x col ll uses hs[ll..ll+2]
    hs[i] = ((unsigned)gl < 2048u) ? hb[r*Lc + gl] : 0.f;
  }
  for (int i = tid; i < 1536; i += 512) dws[i] = dynW[s*1536 + i];
  int cgx = tid & 63;
  float4 bg0 = *(const float4*)&dynB[s*Cc + cgx*8];
  float4 bg4 = *(const float4*)&dynB[s*Cc + cgx*8 + 4];

  #define LOADAF(ch_, AF_) {                                                  \
    _Pragma("unroll")                                                         \
    for (int mi = 0; mi < 4; mi++)                                            \
      (AF_)[mi] = *(const bf16x8*)&W1p[(((ch_)*32 + w*4 + mi) << 9) + lane8]; \
  }

  bf16x8 afA[4], afB[4];
  LOADAF(0, afA);              // overlap with x-compute below
  __syncthreads();

  // -------- compute x once: thread = (cg 0..63, lg=w 0..7), 16 cols --------
  {
    int cg = cgx;
    int q = cg >> 2;
    float wvv[24];
    const float4* wp4 = (const float4*)dws;
    #pragma unroll
    for (int i = 0; i < 6; i++) {
      float4 v = wp4[i*64 + cg];             // lane-consecutive: conflict-free
      wvv[4*i] = v.x; wvv[4*i+1] = v.y; wvv[4*i+2] = v.z; wvv[4*i+3] = v.w;
    }
    float bxx[8];
    bxx[0]=bg0.x; bxx[1]=bg0.y; bxx[2]=bg0.z; bxx[3]=bg0.w;
    bxx[4]=bg4.x; bxx[5]=bg4.y; bxx[6]=bg4.z; bxx[7]=bg4.w;
    const float* hr = hs + q*132;
    int ll0 = w*16;
    float hm = hr[ll0], hc = hr[ll0+1];
    #pragma unroll
    for (int i = 0; i < 16; i++) {
      int ll = ll0 + i;
      float hp = hr[ll+2];
      float v0 = fmaxf(wvv[0]*hm  + wvv[1]*hc  + wvv[2]*hp  + bxx[0], 0.f);
      float v1 = fmaxf(wvv[3]*hm  + wvv[4]*hc  + wvv[5]*hp  + bxx[1], 0.f);
      float v2 = fmaxf(wvv[6]*hm  + wvv[7]*hc  + wvv[8]*hp  + bxx[2], 0.f);
      float v3 = fmaxf(wvv[9]*hm  + wvv[10]*hc + wvv[11]*hp + bxx[3], 0.f);
      float v4 = fmaxf(wvv[12]*hm + wvv[13]*hc + wvv[14]*hp + bxx[4], 0.f);
      float v5 = fmaxf(wvv[15]*hm + wvv[16]*hc + wvv[17]*hp + bxx[5], 0.f);
      float v6 = fmaxf(wvv[18]*hm + wvv[19]*hc + wvv[20]*hp + bxx[6], 0.f);
      float v7 = fmaxf(wvv[21]*hm + wvv[22]*hc + wvv[23]*hp + bxx[7], 0.f);
      uint4 st;
      st.x = cvt_pk_bf16(v0, v1);
      st.y = cvt_pk_bf16(v2, v3);
      st.z = cvt_pk_bf16(v4, v5);
      st.w = cvt_pk_bf16(v6, v7);
      *(uint4*)&xt[xoff(ll, cg)] = st;     // 16B aligned
      hm = hc; hc = hp;
    }
  }

  floatx4 acc[4][8];
  #pragma unroll
  for (int mi = 0; mi < 4; mi++)
    #pragma unroll
    for (int ni = 0; ni < 8; ni++)
      acc[mi][ni] = (floatx4){0.f,0.f,0.f,0.f};

  // Precomputed swizzle bases for phase A B-fragment reads:
  // xoff(ni*16+ln16, ch*4+quad) = X + 32*e4 + ch*32 (ch even)
  //                             = X - 32*e4 + ch*32 (ch odd)
  int e4 = (ln16 >> 2) & 1;
  int bE[8], bO[8];
  #pragma unroll
  for (int ni = 0; ni < 8; ni++) {
    int row = ni*16 + ln16;
    int X = row*512 + ((quad ^ (ln16 & 3)) << 3);
    bE[ni] = X + 32*e4;
    bO[ni] = X - 32*e4;
  }

  #define CHUNK(ch_, AFC_, AFN_, PF_) {                                       \
    bf16x8 bfr[8];                                                            \
    _Pragma("unroll")                                                         \
    for (int ni = 0; ni < 8; ni++)                                            \
      bfr[ni] = *(const bf16x8*)&xt[(((ch_) & 1) ? bO[ni] : bE[ni]) + (ch_)*32]; \
    if (PF_) LOADAF((ch_) + 1, AFN_);                                         \
    __builtin_amdgcn_s_setprio(1);                                            \
    _Pragma("unroll")                                                         \
    for (int ni = 0; ni < 8; ni++)                                            \
      _Pragma("unroll")                                                       \
      for (int mi = 0; mi < 4; mi++)                                          \
        acc[mi][ni] = __builtin_amdgcn_mfma_f32_16x16x32_bf16((AFC_)[mi], bfr[ni], acc[mi][ni], 0, 0, 0); \
    __builtin_amdgcn_s_setprio(0);                                            \
  }

  __syncthreads();   // x ready

  // -------- phase A: 16 K-chunks, barrier-free, af double-buffered --------
  #pragma unroll 1
  for (int cp = 0; cp < 8; cp++) {
    CHUNK(2*cp,     afA, afB, 1);
    CHUNK(2*cp + 1, afB, afA, (cp < 7));
  }
  __syncthreads();   // all x reads done before x2 overwrites the region

  // -------- epilogue A: relu+b1 -> x2 in xt (bf16), zero invalid l;
  //          plus h1 passthrough (independent global traffic, overlaps) -----
  #pragma unroll
  for (int mi = 0; mi < 4; mi++) {
    int o = w*64 + mi*16 + quad*4;
    float4 b1v = *(const float4*)(b1 + o);
    int cg = o >> 3, half = (quad & 1)*4;
    #pragma unroll
    for (int ni = 0; ni < 8; ni++) {
      int ll = ni*16 + ln16;
      int gl = lb + ll;
      uint2 st;
      if ((unsigned)gl < 2048u) {
        st.x = cvt_pk_bf16(fmaxf(acc[mi][ni][0] + b1v.x, 0.f),
                           fmaxf(acc[mi][ni][1] + b1v.y, 0.f));
        st.y = cvt_pk_bf16(fmaxf(acc[mi][ni][2] + b1v.z, 0.f),
                           fmaxf(acc[mi][ni][3] + b1v.w, 0.f));
      } else {
        st.x = 0u; st.y = 0u;              // conv2 zero-pad columns
      }
      *(uint2*)&xt[xoff(ll, cg) + half] = st;
    }
  }
  // h1 passthrough: rows q 0..15, cols l = lb+1 .. lb+126 (all 8 waves)
  #pragma unroll
  for (int i = 0; i < 4; i++) {
    int idx = tid + i*512;               // 0..2047 = (q 0..15) x (ll 0..127)
    int ll = idx & 127, q = idx >> 7;
    int l = lb + ll;
    if (ll >= 1 && ll <= ULL && l < 2048) {
      int gi = s*(NSQ*Lc) + q*Lc + l;
      out[gi] = h[gi];
    }
  }
  __syncthreads();

  // -------- phase B: 8 waves = (lq 0..3 [32 lpos each], jh 0..1) ----------
  {
    int lq = w >> 1, jh = w & 1;
    floatx4 ca[2];
    ca[0] = (floatx4){0.f,0.f,0.f,0.f};
    ca[1] = (floatx4){0.f,0.f,0.f,0.f};
    __builtin_amdgcn_s_setprio(1);
    #pragma unroll
    for (int k = 0; k < 3; k++) {
      int bEk[2], bOk[2];
      #pragma unroll
      for (int n2 = 0; n2 < 2; n2++) {
        int rr = lq*32 + n2*16 + ln16 - 1 + k;
        rr = (rr < 0) ? 0 : ((rr > 127) ? 127 : rr);   // edges discarded
        int er = (rr >> 2) & 1;
        int Xk = rr*512 + ((quad ^ (rr & 3)) << 3);
        bEk[n2] = Xk + 32*er; bOk[n2] = Xk - 32*er;
      }
      #pragma unroll
      for (int cc = 0; cc < 16; cc++) {
        bf16x8 a0 = *(const bf16x8*)&W2p[(((k*2 + jh)*16 + cc) << 9) + lane8];
        bf16x8 v0 = *(const bf16x8*)&xt[((cc & 1) ? bOk[0] : bEk[0]) + cc*32];
        ca[0] = __builtin_amdgcn_mfma_f32_16x16x32_bf16(a0, v0, ca[0], 0, 0, 0);
        bf16x8 v1 = *(const bf16x8*)&xt[((cc & 1) ? bOk[1] : bEk[1]) + cc*32];
        ca[1] = __builtin_amdgcn_mfma_f32_16x16x32_bf16(a0, v1, ca[1], 0, 0, 0);
      }
    }
    __builtin_amdgcn_s_setprio(0);
    float4 b2v = *(const float4*)(b2 + jh*16 + quad*4);
    #pragma unroll
    for (int n2 = 0; n2 < 2; n2++) {
      int ll = lq*32 + n2*16 + ln16;
      float4 st;
      st.x = ca[n2][0] + b2v.x; st.y = ca[n2][1] + b2v.y;
      st.z = ca[n2][2] + b2v.z; st.w = ca[n2][3] + b2v.w;
      *(float4*)&x3b[ll*37 + jh*16 + quad*4] = st;
    }
  }

  // prefetch phase-C h2 values: loads in flight across the barrier wait
  float hpre[4]; int gidx2[4]; bool val2[4];
  #pragma unroll
  for (int i = 0; i < 4; i++) {
    int idx = tid + i*512;           // 0..2047 = (q16 0..15) x (ll 0..127)
    int ll = idx & 127, q = 16 + (idx >> 7);
    int l = lb + ll;
    val2[i] = (ll >= 1 && ll <= ULL && l < 2048);
    gidx2[i] = s*(NSQ*Lc) + q*Lc + l;
    hpre[i] = val2[i] ? h[gidx2[i]] : 0.f;
  }
  __syncthreads();

  // -------- phase C: h2 rows only: sigmoid/affine/out + logdet --------
  float ld = 0.f;
  #pragma unroll
  for (int i = 0; i < 4; i++) {
    int idx = tid + i*512;
    int ll = idx & 127, q16 = idx >> 7;
    if (val2[i]) {
      float sv = 1.f / (1.f + __expf(-(x3b[ll*37 + q16] + 2.f))) + 1e-7f;
      float mv = x3b[ll*37 + q16 + 16];
      out[gidx2[i]] = sv * (hpre[i] + mv);
      ld += __logf(sv);
    }
  }
  #pragma unroll
  for (int off = 32; off > 0; off >>= 1) ld += __shfl_down(ld, off);
  if ((tid & 63) == 0) red[w] = ld;
  __syncthreads();
  if (tid == 0) {
    float tot = 0.f;
    #pragma unroll
    for (int i = 0; i < 8; i++) tot += red[i];
    atomicAdd(&out[OUT_H + s], tot);
  }
}

// ---------------------------------------------------------------------------
extern "C" void kernel_launch(void* const* d_in, const int* in_sizes, int n_in,
                              void* d_out, int out_size, void* d_ws, size_t ws_size,
                              hipStream_t stream) {
  const float* h   = (const float*)d_in[0];
  const float* emb = (const float*)d_in[1];
  const float* Wa  = (const float*)d_in[2];
  const float* ba  = (const float*)d_in[3];
  const float* Wb  = (const float*)d_in[4];
  const float* bb  = (const float*)d_in[5];
  const float* W1  = (const float*)d_in[6];
  const float* b1  = (const float*)d_in[7];
  const float* W2  = (const float*)d_in[8];
  const float* b2  = (const float*)d_in[9];
  float* out = (float*)d_out;
  char* ws = (char*)d_ws;

  float* dynW = (float*)(ws + 0);                          // 384 KiB (transposed)
  float* dynB = (float*)(ws + 393216);                     // 128 KiB
  unsigned short* W1p = (unsigned short*)(ws + 524288);    // 512 KiB (packed)
  unsigned short* W2p = (unsigned short*)(ws + 1048576);   // 96 KiB (packed)
  if (ws_size < 1179648ull) return;                        // ~1.2 MB needed

  const int smem_bytes = 150048;  // stage/x3b 18944 + xt 131072 + red 32
  (void)hipFuncSetAttribute((const void*)k_fused13,
                            hipFuncAttributeMaxDynamicSharedMemorySize,
                            smem_bytes);

  k_prep<<<1024, 256, 0, stream>>>(emb, Wa, ba, Wb, bb, W1, W2,
                                   dynW, dynB, W1p, W2p, out);
  k_fused13<<<dim3(NT, 64), 512, smem_bytes, stream>>>(h, W1p, b1, W2p, b2,
                                                       dynW, dynB, out);
}

// Round 5
// 187.127 us; speedup vs baseline: 1.1177x; 1.1177x over previous
//
#include <hip/hip_runtime.h>
#include <stdint.h>

#define S 64
#define NSQ 32
#define Lc 2048
#define Cc 512
#define Ec 128
#define OUT_H (S*NSQ*Lc)   /* 4194304 */

typedef __bf16 bf16x8 __attribute__((ext_vector_type(8)));
typedef float floatx4 __attribute__((ext_vector_type(4)));

__device__ __forceinline__ unsigned short f2bf(float f){
  union { float f; uint32_t u; } v; v.f = f;
  uint32_t r = v.u + 0x7fffu + ((v.u >> 16) & 1u);
  return (unsigned short)(r >> 16);
}

// packed f32x2 -> bf16x2 (RNE), 1 instruction on gfx950
__device__ __forceinline__ uint32_t cvt_pk_bf16(float lo, float hi){
  uint32_t r;
  asm("v_cvt_pk_bf16_f32 %0, %1, %2" : "=v"(r) : "v"(lo), "v"(hi));
  return r;
}

// XOR-swizzled LDS offset (shorts) for the x/x2 tile (row stride 512).
__device__ __forceinline__ int xoff(int row, int cg) {
  return row*512 + (((cg) ^ (row & 7)) << 3);
}

// ---------------------------------------------------------------------------
// k_prep v2 — latency-lean:
//  - adapt: one row per 16-lane group (8 iters/block), 4 DPP-width shuffle
//    steps (no cross-row xor16), coalesced 512B row loads
//  - W1 pack: coalesced float2 source reads (source order), scattered packed
//    writes (stores don't stall); one float2 per thread, gtid < 131072
//  - W2 pack + logdet zero on the remaining threads
// grid 1024 x 256.
// dynW transposed: thread cg reads float4 j4 at dynW[s*1536 + j4*256 + cg*4+..]
// W1p: frag = ch*32 + o16; elem(lane,j) = W1[o16*16+(lane&15)][ch*32+(lane>>4)*8+j]
// W2p: frag = (k*2+jh)*16 + cc; elem(lane,j) = W2[jh*16+(lane&15)][cc*32+(lane>>4)*8+j][k]
// ---------------------------------------------------------------------------
__global__ void __launch_bounds__(256) k_prep(
                       const float* __restrict__ emb,
                       const float* __restrict__ Wa, const float* __restrict__ ba,
                       const float* __restrict__ Wb, const float* __restrict__ bb,
                       const float* __restrict__ W1, const float* __restrict__ W2,
                       float* __restrict__ dynW, float* __restrict__ dynB,
                       unsigned short* __restrict__ W1p, unsigned short* __restrict__ W2p,
                       float* __restrict__ out)
{
  __shared__ float embl[Ec];
  int tid = threadIdx.x;
  int b = blockIdx.x;          // 1024 blocks, 16 per sample for adapt
  int s = b >> 4, g = b & 15;
  if (tid < Ec) embl[tid] = emb[s*Ec + tid];
  __syncthreads();
  {
    int grp = tid >> 4, le = tid & 15;
    float4 e0 = *(const float4*)&embl[le*8];
    float4 e1 = *(const float4*)&embl[le*8 + 4];
    int base_o = g*128 + grp;
    #pragma unroll
    for (int p = 0; p < 8; p++) {
      int ro = base_o + p*16;
      bool isA = ro < 1536;
      const float* rp = isA ? (Wa + ro*Ec) : (Wb + (ro - 1536)*Ec);
      float4 w0 = *(const float4*)&rp[le*8];
      float4 w1 = *(const float4*)&rp[le*8 + 4];
      float part = w0.x*e0.x + w0.y*e0.y + w0.z*e0.z + w0.w*e0.w
                 + w1.x*e1.x + w1.y*e1.y + w1.z*e1.z + w1.w*e1.w;
      part += __shfl_xor(part, 1, 16);
      part += __shfl_xor(part, 2, 16);
      part += __shfl_xor(part, 4, 16);
      part += __shfl_xor(part, 8, 16);
      if (le == 0) {
        if (isA) {
          int ch = ro / 3, k = ro - ch*3;
          int cgc = ch >> 3, j = (ch & 7)*3 + k;
          dynW[s*1536 + (j >> 2)*256 + cgc*4 + (j & 3)] = part + ba[ro];
        } else {
          dynB[s*Cc + (ro - 1536)] = part + bb[ro - 1536];
        }
      }
    }
  }

  int gtid = b*256 + tid;      // 0..262143
  if (gtid < 131072) {
    // W1 pack: source-order coalesced float2 reads, scattered uint32 writes
    int e2 = gtid*2;                       // even source index
    int oo = e2 >> 9, cc = e2 & 511;
    int frag = (cc >> 5)*32 + (oo >> 4);
    int lane = ((cc >> 3) & 3)*16 + (oo & 15);
    int j = cc & 7;                        // even
    float2 wv = *(const float2*)&W1[e2];
    ((uint32_t*)W1p)[(frag << 8) + lane*4 + (j >> 1)] = cvt_pk_bf16(wv.x, wv.y);
  } else {
    int t2 = gtid - 131072;
    if (t2 < 49152) {
      // W2 pack: coalesced source reads, scattered 2B dest writes
      int e = t2;
      int jj = e / 1536;
      int r = e - jj*1536;
      int c = r / 3, k = r - c*3;
      int cc_ = c >> 5, hi = (c >> 3) & 3, j = c & 7;
      int jh = jj >> 4, lo = jj & 15;
      int lane = hi*16 + lo;
      int frag = (k*2 + jh)*16 + cc_;
      W2p[(frag << 9) + lane*8 + j] = f2bf(W2[e]);
    } else if (t2 < 49152 + S) {
      out[OUT_H + (t2 - 49152)] = 0.f;     // logdet accumulators
    }
  }
}

// ---------------------------------------------------------------------------
// k_fused12 (R3 version, measured ~121 us — reverted from the R4 128-col
// experiment which lost occupancy):
//  - 64-col l-tile, 2 blocks/CU, phase B all-8-waves conv, h1 copy in
//    epilogue A, bfr ds_reads before af global loads, setprio on MFMA.
// x2 col ll <-> global l = t*62 - 1 + ll; valid outputs ll in [1,62].
// ---------------------------------------------------------------------------
__global__ void __launch_bounds__(512, 4) k_fused12(
    const float* __restrict__ h,
    const unsigned short* __restrict__ W1p, const float* __restrict__ b1,
    const unsigned short* __restrict__ W2p, const float* __restrict__ b2,
    const float* __restrict__ dynW, const float* __restrict__ dynB,
    float* __restrict__ out)
{
  extern __shared__ char smem[];
  float* hs  = (float*)smem;                              // [16][68] f32 (4352 B)
  float* dws = (float*)(smem + 4352);                     // [6][64] float4 (6144 B)
  float* x3b = (float*)smem;                              // [64][37] f32 (aliases stage)
  unsigned short* xt = (unsigned short*)(smem + 10496);   // [64][512] swizzled (64 KiB)
  float* red = (float*)(smem + 76032);                    // [8]

  int tid = threadIdx.x;
  int t = blockIdx.x, s = blockIdx.y;
  int lb = t*62 - 1;           // global l of x2 col ll=0
  int w = tid >> 6, ln16 = tid & 15, quad = (tid & 63) >> 4;
  int lane8 = (tid & 63)*8;

  const float* hb = h + s*(NSQ*Lc);

  // -------- stage h window + dyn weights (+ bias from L2, pre-barrier) -----
  for (int i = tid; i < 16*68; i += 512) {
    int r = i / 68, col = i - r*68;
    int gl = t*62 - 2 + col;                  // x col ll uses hs[ll..ll+2]
    hs[i] = ((unsigned)gl < 2048u) ? hb[r*Lc + gl] : 0.f;
  }
  for (int i = tid; i < 1536; i += 512) dws[i] = dynW[s*1536 + i];
  int cgx = tid & 63;
  float4 bg0 = *(const float4*)&dynB[s*Cc + cgx*8];
  float4 bg4 = *(const float4*)&dynB[s*Cc + cgx*8 + 4];

  #define LOADAF(ch_, AF_) {                                                  \
    _Pragma("unroll")                                                         \
    for (int mi = 0; mi < 4; mi++)                                            \
      (AF_)[mi] = *(const bf16x8*)&W1p[(((ch_)*32 + w*4 + mi) << 9) + lane8]; \
  }

  bf16x8 afA[4], afB[4];
  LOADAF(0, afA);              // overlap with x-compute below
  __syncthreads();

  // -------- compute x once: thread = (cg 0..63, lg=w 0..7), 8 cols --------
  {
    int cg = cgx;
    int q = cg >> 2;
    float wvv[24];
    const float4* wp4 = (const float4*)dws;
    #pragma unroll
    for (int i = 0; i < 6; i++) {
      float4 v = wp4[i*64 + cg];             // lane-consecutive: conflict-free
      wvv[4*i] = v.x; wvv[4*i+1] = v.y; wvv[4*i+2] = v.z; wvv[4*i+3] = v.w;
    }
    float bxx[8];
    bxx[0]=bg0.x; bxx[1]=bg0.y; bxx[2]=bg0.z; bxx[3]=bg0.w;
    bxx[4]=bg4.x; bxx[5]=bg4.y; bxx[6]=bg4.z; bxx[7]=bg4.w;
    const float* hr = hs + q*68;
    int ll0 = w*8;
    float hm = hr[ll0], hc = hr[ll0+1];
    #pragma unroll
    for (int i = 0; i < 8; i++) {
      int ll = ll0 + i;
      float hp = hr[ll+2];
      float v0 = fmaxf(wvv[0]*hm  + wvv[1]*hc  + wvv[2]*hp  + bxx[0], 0.f);
      float v1 = fmaxf(wvv[3]*hm  + wvv[4]*hc  + wvv[5]*hp  + bxx[1], 0.f);
      float v2 = fmaxf(wvv[6]*hm  + wvv[7]*hc  + wvv[8]*hp  + bxx[2], 0.f);
      float v3 = fmaxf(wvv[9]*hm  + wvv[10]*hc + wvv[11]*hp + bxx[3], 0.f);
      float v4 = fmaxf(wvv[12]*hm + wvv[13]*hc + wvv[14]*hp + bxx[4], 0.f);
      float v5 = fmaxf(wvv[15]*hm + wvv[16]*hc + wvv[17]*hp + bxx[5], 0.f);
      float v6 = fmaxf(wvv[18]*hm + wvv[19]*hc + wvv[20]*hp + bxx[6], 0.f);
      float v7 = fmaxf(wvv[21]*hm + wvv[22]*hc + wvv[23]*hp + bxx[7], 0.f);
      uint4 st;
      st.x = cvt_pk_bf16(v0, v1);
      st.y = cvt_pk_bf16(v2, v3);
      st.z = cvt_pk_bf16(v4, v5);
      st.w = cvt_pk_bf16(v6, v7);
      *(uint4*)&xt[xoff(ll, cg)] = st;     // 16B aligned (xoff multiple of 8 shorts)
      hm = hc; hc = hp;
    }
  }

  floatx4 acc[4][4];
  #pragma unroll
  for (int mi = 0; mi < 4; mi++)
    #pragma unroll
    for (int ni = 0; ni < 4; ni++)
      acc[mi][ni] = (floatx4){0.f,0.f,0.f,0.f};

  // Precomputed swizzle bases for phase A B-fragment reads:
  // xoff(ni*16+ln16, ch*4+quad) = X + 32*e4 + ch*32 (ch even)
  //                             = X - 32*e4 + ch*32 (ch odd)
  int e4 = (ln16 >> 2) & 1;
  int bE[4], bO[4];
  #pragma unroll
  for (int ni = 0; ni < 4; ni++) {
    int row = ni*16 + ln16;
    int X = row*512 + ((quad ^ (ln16 & 3)) << 3);
    bE[ni] = X + 32*e4;
    bO[ni] = X - 32*e4;
  }

  #define CHUNK(ch_, AFC_, AFN_, PF_) {                                       \
    bf16x8 bfr[4];                                                            \
    _Pragma("unroll")                                                         \
    for (int ni = 0; ni < 4; ni++)                                            \
      bfr[ni] = *(const bf16x8*)&xt[(((ch_) & 1) ? bO[ni] : bE[ni]) + (ch_)*32]; \
    if (PF_) LOADAF((ch_) + 1, AFN_);                                         \
    __builtin_amdgcn_s_setprio(1);                                            \
    _Pragma("unroll")                                                         \
    for (int ni = 0; ni < 4; ni++)                                            \
      _Pragma("unroll")                                                       \
      for (int mi = 0; mi < 4; mi++)                                          \
        acc[mi][ni] = __builtin_amdgcn_mfma_f32_16x16x32_bf16((AFC_)[mi], bfr[ni], acc[mi][ni], 0, 0, 0); \
    __builtin_amdgcn_s_setprio(0);                                            \
  }

  __syncthreads();   // x ready

  // -------- phase A: 16 K-chunks, barrier-free, af double-buffered --------
  #pragma unroll 1
  for (int cp = 0; cp < 8; cp++) {
    CHUNK(2*cp,     afA, afB, 1);
    CHUNK(2*cp + 1, afB, afA, (cp < 7));
  }
  __syncthreads();   // all x reads done before x2 overwrites the region

  // -------- epilogue A: relu+b1 -> x2 in xt (bf16), zero invalid l;
  //          plus h1 passthrough (independent global traffic, overlaps) -----
  #pragma unroll
  for (int mi = 0; mi < 4; mi++) {
    int o = w*64 + mi*16 + quad*4;
    float4 b1v = *(const float4*)(b1 + o);
    int cg = o >> 3, half = (quad & 1)*4;
    #pragma unroll
    for (int ni = 0; ni < 4; ni++) {
      int ll = ni*16 + ln16;
      int gl = lb + ll;
      uint2 st;
      if ((unsigned)gl < 2048u) {
        st.x = cvt_pk_bf16(fmaxf(acc[mi][ni][0] + b1v.x, 0.f),
                           fmaxf(acc[mi][ni][1] + b1v.y, 0.f));
        st.y = cvt_pk_bf16(fmaxf(acc[mi][ni][2] + b1v.z, 0.f),
                           fmaxf(acc[mi][ni][3] + b1v.w, 0.f));
      } else {
        st.x = 0u; st.y = 0u;              // conv2 zero-pad columns
      }
      *(uint2*)&xt[xoff(ll, cg) + half] = st;
    }
  }
  // h1 passthrough: rows q 0..15, cols l = lb+1 .. lb+62 (all 8 waves)
  #pragma unroll
  for (int i = 0; i < 2; i++) {
    int idx = tid + i*512;               // 0..1023 = (q 0..15) x (ll 0..63)
    int ll = idx & 63, q = idx >> 6;
    int l = lb + ll;
    if (ll >= 1 && ll <= 62 && l < 2048) {
      int gi = s*(NSQ*Lc) + q*Lc + l;
      out[gi] = h[gi];
    }
  }
  __syncthreads();

  // -------- phase B: all 8 waves conv; wave = (lq = w>>1, jh = w&1) --------
  {
    int lq = w >> 1, jh = w & 1;
    int ll = lq*16 + ln16;
    floatx4 ca = (floatx4){0.f,0.f,0.f,0.f};
    __builtin_amdgcn_s_setprio(1);
    #pragma unroll
    for (int k = 0; k < 3; k++) {
      int rr = ll - 1 + k;
      rr = (rr < 0) ? 0 : ((rr > 63) ? 63 : rr);   // edges discarded
      // xoff(rr, cc*4+quad) = Xk +- 32*er + cc*32 (sign by cc parity)
      int er = (rr >> 2) & 1;
      int Xk = rr*512 + ((quad ^ (rr & 3)) << 3);
      int bEk = Xk + 32*er, bOk = Xk - 32*er;
      #pragma unroll
      for (int cc = 0; cc < 16; cc++) {
        bf16x8 v0 = *(const bf16x8*)&xt[((cc & 1) ? bOk : bEk) + cc*32];
        bf16x8 a0 = *(const bf16x8*)&W2p[(((k*2 + jh)*16 + cc) << 9) + lane8];
        ca = __builtin_amdgcn_mfma_f32_16x16x32_bf16(a0, v0, ca, 0, 0, 0);
      }
    }
    __builtin_amdgcn_s_setprio(0);
    float4 b2v = *(const float4*)(b2 + jh*16 + quad*4);
    float4 st;
    st.x = ca[0] + b2v.x; st.y = ca[1] + b2v.y;
    st.z = ca[2] + b2v.z; st.w = ca[3] + b2v.w;
    *(float4*)&x3b[ll*37 + jh*16 + quad*4] = st;
  }

  // prefetch phase-C h2 values: loads in flight across the barrier wait
  float hpre[2]; int gidx2[2]; bool val2[2];
  #pragma unroll
  for (int i = 0; i < 2; i++) {
    int idx = tid + i*512;           // 0..1023 = (q16 0..15) x (ll 0..63)
    int ll = idx & 63, q = 16 + (idx >> 6);
    int l = lb + ll;
    val2[i] = (ll >= 1 && ll <= 62 && l < 2048);
    gidx2[i] = s*(NSQ*Lc) + q*Lc + l;
    hpre[i] = val2[i] ? h[gidx2[i]] : 0.f;
  }
  __syncthreads();

  // -------- phase C: h2 rows only: sigmoid/affine/out + logdet --------
  float ld = 0.f;
  #pragma unroll
  for (int i = 0; i < 2; i++) {
    int idx = tid + i*512;
    int ll = idx & 63, q16 = idx >> 6;
    if (val2[i]) {
      float sv = 1.f / (1.f + __expf(-(x3b[ll*37 + q16] + 2.f))) + 1e-7f;
      float mv = x3b[ll*37 + q16 + 16];
      out[gidx2[i]] = sv * (hpre[i] + mv);
      ld += __logf(sv);
    }
  }
  #pragma unroll
  for (int off = 32; off > 0; off >>= 1) ld += __shfl_down(ld, off);
  if ((tid & 63) == 0) red[w] = ld;
  __syncthreads();
  if (tid == 0) {
    float tot = 0.f;
    #pragma unroll
    for (int i = 0; i < 8; i++) tot += red[i];
    atomicAdd(&out[OUT_H + s], tot);
  }
}

// ---------------------------------------------------------------------------
extern "C" void kernel_launch(void* const* d_in, const int* in_sizes, int n_in,
                              void* d_out, int out_size, void* d_ws, size_t ws_size,
                              hipStream_t stream) {
  const float* h   = (const float*)d_in[0];
  const float* emb = (const float*)d_in[1];
  const float* Wa  = (const float*)d_in[2];
  const float* ba  = (const float*)d_in[3];
  const float* Wb  = (const float*)d_in[4];
  const float* bb  = (const float*)d_in[5];
  const float* W1  = (const float*)d_in[6];
  const float* b1  = (const float*)d_in[7];
  const float* W2  = (const float*)d_in[8];
  const float* b2  = (const float*)d_in[9];
  float* out = (float*)d_out;
  char* ws = (char*)d_ws;

  float* dynW = (float*)(ws + 0);                          // 384 KiB (transposed)
  float* dynB = (float*)(ws + 393216);                     // 128 KiB
  unsigned short* W1p = (unsigned short*)(ws + 524288);    // 512 KiB (packed)
  unsigned short* W2p = (unsigned short*)(ws + 1048576);   // 96 KiB (packed)
  if (ws_size < 1179648ull) return;                        // ~1.2 MB needed

  const int smem_bytes = 76064;  // stage/x3b 10496 + xt 65536 + red 32
  (void)hipFuncSetAttribute((const void*)k_fused12,
                            hipFuncAttributeMaxDynamicSharedMemorySize,
                            smem_bytes);

  k_prep<<<1024, 256, 0, stream>>>(emb, Wa, ba, Wb, bb, W1, W2,
                                   dynW, dynB, W1p, W2p, out);
  k_fused12<<<dim3(34, 64), 512, smem_bytes, stream>>>(h, W1p, b1, W2p, b2,
                                                       dynW, dynB, out);
}